// Round 8
// baseline (314.165 us; speedup 1.0000x reference)
//
#include <hip/hip_runtime.h>
#include <hip/hip_bf16.h>
#include <stdint.h>

#define DM 768
#define DFF 3072
#define NH 12
#define DK 64
#define SS 2048
#define NTOK 4096   // B*S = 2*2048
#define KCH 4       // attention k-chunks (split-S, no-max softmax => partials are pure sums)

typedef __hip_bfloat16 bf16;
typedef short bf16x8 __attribute__((ext_vector_type(8)));
typedef float f32x4 __attribute__((ext_vector_type(4)));

#define MFMA16(a, b, c) __builtin_amdgcn_mfma_f32_16x16x32_bf16((a), (b), (c), 0, 0, 0)

// 0.125 (1/sqrt(Dk)) * log2(e), folded into the Q projection so attention uses exp2f
#define QSCALE 0.18033688011112042f

static __device__ __forceinline__ bf16 f2b(float f) { return __float2bfloat16(f); }
static __device__ __forceinline__ unsigned short f2b_bits(float f) {
    bf16 h = __float2bfloat16(f);
    return *reinterpret_cast<unsigned short*>(&h);
}
static __device__ __forceinline__ float b2f(bf16 h) { return __bfloat162float(h); }

// async 16B global->LDS DMA. LDS dest must be wave-uniform base + lane*16.
static __device__ __forceinline__ void g2l16(const void* g, void* l) {
    __builtin_amdgcn_global_load_lds(
        (const __attribute__((address_space(1))) unsigned int*)g,
        (__attribute__((address_space(3))) unsigned int*)(uintptr_t)l,
        16, 0, 0);
}

// ---------------- all 6 weight transposes (fp32->bf16, [K,N]->[N,K]) --------
__global__ __launch_bounds__(256) void transpose_all(const float* Wq, const float* Wk,
                                                     const float* Wv, const float* Wo,
                                                     const float* W1, const float* W2,
                                                     bf16* WqT, bf16* WkT, bf16* WvT,
                                                     bf16* WoT, bf16* W1T, bf16* W2T) {
    __shared__ float tile[32][33];
    int id = blockIdx.x;
    const float* W; bf16* WT; int K, N, n0, k0;
    if (id < 2304) {            // Wq/Wk/Wv/Wo: 768x768, 24x24 blocks each
        int z = id / 576, r = id % 576;
        W  = (z == 0) ? Wq : (z == 1) ? Wk : (z == 2) ? Wv : Wo;
        WT = (z == 0) ? WqT : (z == 1) ? WkT : (z == 2) ? WvT : WoT;
        K = 768; N = 768; n0 = (r % 24) * 32; k0 = (r / 24) * 32;
    } else if (id < 4608) {     // W1: [768,3072] -> [3072,768]
        int r = id - 2304; W = W1; WT = W1T;
        K = 768; N = 3072; n0 = (r % 96) * 32; k0 = (r / 96) * 32;
    } else {                    // W2: [3072,768] -> [768,3072]
        int r = id - 4608; W = W2; WT = W2T;
        K = 3072; N = 768; n0 = (r % 24) * 32; k0 = (r / 24) * 32;
    }
    int tx = threadIdx.x & 31, ty = threadIdx.x >> 5;
#pragma unroll
    for (int r = ty; r < 32; r += 8)
        tile[r][tx] = W[(size_t)(k0 + r) * N + n0 + tx];
    __syncthreads();
#pragma unroll
    for (int r = ty; r < 32; r += 8)
        WT[(size_t)(n0 + r) * K + k0 + tx] = f2b(tile[tx][r]);
}

// ---------------- LayerNorm (unbiased var, eps on std) --------
__global__ __launch_bounds__(256) void ln_fwd(const float* __restrict__ x,
                                              const float* __restrict__ g,
                                              const float* __restrict__ be,
                                              bf16* __restrict__ out) {
    int wid = threadIdx.x >> 6, lane = threadIdx.x & 63;
    int row = blockIdx.x * 4 + wid;
    const float* xr = x + (size_t)row * DM;
    float v[12];
    float s = 0.f;
#pragma unroll
    for (int i = 0; i < 12; ++i) { v[i] = xr[lane + i * 64]; s += v[i]; }
#pragma unroll
    for (int off = 32; off >= 1; off >>= 1) s += __shfl_xor(s, off);
    float mean = s * (1.f / 768.f);
    float s2 = 0.f;
#pragma unroll
    for (int i = 0; i < 12; ++i) { float d = v[i] - mean; s2 += d * d; }
#pragma unroll
    for (int off = 32; off >= 1; off >>= 1) s2 += __shfl_xor(s2, off);
    float rstd = 1.f / (sqrtf(s2 * (1.f / 767.f)) + 1e-6f);
    bf16* orow = out + (size_t)row * DM;
#pragma unroll
    for (int i = 0; i < 12; ++i) {
        int c = lane + i * 64;
        orow[c] = f2b(g[c] * (v[i] - mean) * rstd + be[c]);
    }
}

// ---------------- 128x128 GEMM core, BK=64, single buffer, 2 barriers/iter ---
// 64-elem rows (8 chunks); chunk c of row r stored at phys c ^ (r&7) -> b128
// reads 2-way max (free). Halved barrier count vs BK=32; 32 MFMA/wave between
// barriers; 5 blocks/CU -> cross-block overlap hides the DMA drain (R5-attn
// proven mechanism). kk-inner loop keeps operand frags at 8 (VGPR pressure).
__device__ __forceinline__ void gemm_core(const bf16* __restrict__ A,
                                          const bf16* __restrict__ BT,
                                          int K, int bm, int bn,
                                          bf16* As, bf16* Bs,   // each 128*64
                                          f32x4 acc[4][4]) {
    int tid = threadIdx.x;
    int lane = tid & 63, quad = lane >> 4, lid = lane & 15;
    int wid = tid >> 6;
    int wm = (wid >> 1) * 64, wn = (wid & 1) * 64;
    const bf16* Ap[4];
    const bf16* Bp[4];
#pragma unroll
    for (int it = 0; it < 4; ++it) {
        int s = tid + it * 256;
        int r = s >> 3, c = (s & 7) ^ (r & 7);
        Ap[it] = A + (size_t)(bm + r) * K + c * 8;
        Bp[it] = BT + (size_t)(bn + r) * K + c * 8;
    }
    int rdc = quad ^ (lid & 7);
    for (int k0 = 0; k0 < K; k0 += 64) {
        __syncthreads();                    // all waves done reading prev iter
#pragma unroll
        for (int it = 0; it < 4; ++it) {
            g2l16(Ap[it] + k0, As + (tid + it * 256) * 8);
            g2l16(Bp[it] + k0, Bs + (tid + it * 256) * 8);
        }
        __syncthreads();                    // vmcnt(0) drain -> data ready
#pragma unroll
        for (int kk = 0; kk < 2; ++kk) {
            int pc = rdc ^ (kk * 4);
            bf16x8 af[4], bfr[4];
#pragma unroll
            for (int i = 0; i < 4; ++i) af[i]  = *(const bf16x8*)&As[(wm + i * 16 + lid) * 64 + pc * 8];
#pragma unroll
            for (int j = 0; j < 4; ++j) bfr[j] = *(const bf16x8*)&Bs[(wn + j * 16 + lid) * 64 + pc * 8];
#pragma unroll
            for (int i = 0; i < 4; ++i)
#pragma unroll
                for (int j = 0; j < 4; ++j)
                    acc[i][j] = MFMA16(af[i], bfr[j], acc[i][j]);
        }
    }
}

// ---------------- fused QKV projection -------------------------------------
__global__ __launch_bounds__(256) void gemm_qkv(const bf16* __restrict__ A,
                                                const bf16* __restrict__ WqT,
                                                const bf16* __restrict__ WkT,
                                                const bf16* __restrict__ WvT,
                                                const float* __restrict__ bq,
                                                const float* __restrict__ bk,
                                                const float* __restrict__ bv,
                                                bf16* __restrict__ qb,
                                                bf16* __restrict__ kb,
                                                bf16* __restrict__ vtb) {
    __shared__ bf16 As[128 * 64];
    __shared__ bf16 Bs[128 * 64];
    int which = blockIdx.x / 6;
    int bn = (blockIdx.x % 6) * 128;
    int bm = blockIdx.y * 128;
    const bf16* BT = (which == 0) ? WqT : (which == 1) ? WkT : WvT;
    const float* bias = (which == 0) ? bq : (which == 1) ? bk : bv;
    f32x4 acc[4][4] = {};
    gemm_core(A, BT, DM, bm, bn, As, Bs, acc);

    int tid = threadIdx.x, wid = tid >> 6, lane = tid & 63, quad = lane >> 4, lid = lane & 15;
    int wm = (wid >> 1) * 64, wn = (wid & 1) * 64;
    float sc = (which == 0) ? QSCALE : 1.f;   // fold softmax scale+log2e into Q
#pragma unroll
    for (int j = 0; j < 4; ++j) {
        int col = bn + wn + j * 16 + lid;
        float bb = bias[col];
        int hh = col >> 6, d = col & 63;
#pragma unroll
        for (int i = 0; i < 4; ++i) {
            int rowbase = bm + wm + i * 16 + quad * 4;
            int b = rowbase >> 11;
            int s0 = rowbase & 2047;
            if (which == 2) {
                ushort4 pk;
                pk.x = f2b_bits(acc[i][j][0] + bb);
                pk.y = f2b_bits(acc[i][j][1] + bb);
                pk.z = f2b_bits(acc[i][j][2] + bb);
                pk.w = f2b_bits(acc[i][j][3] + bb);
                *(ushort4*)&vtb[(((size_t)b * NH + hh) * DK + d) * SS + s0] = pk;
            } else {
                bf16* dst = which ? kb : qb;
#pragma unroll
                for (int r = 0; r < 4; ++r)
                    dst[(((size_t)b * NH + hh) * SS + (s0 + r)) * DK + d] = f2b((acc[i][j][r] + bb) * sc);
            }
        }
    }
}

// ---------------- 128x128 GEMM with epilogues (FFN1) ---------------
template <int EPI>
__global__ __launch_bounds__(256) void gemm_ep(const bf16* __restrict__ A,
                                               const bf16* __restrict__ BT,
                                               const float* __restrict__ bias,
                                               const float* __restrict__ res,
                                               void* __restrict__ outp,
                                               int N, int K) {
    __shared__ bf16 As[128 * 64];
    __shared__ bf16 Bs[128 * 64];
    int bm = blockIdx.y * 128, bn = blockIdx.x * 128;
    f32x4 acc[4][4] = {};
    gemm_core(A, BT, K, bm, bn, As, Bs, acc);

    int tid = threadIdx.x, wid = tid >> 6, lane = tid & 63, quad = lane >> 4, lid = lane & 15;
    int wm = (wid >> 1) * 64, wn = (wid & 1) * 64;
#pragma unroll
    for (int j = 0; j < 4; ++j) {
        int col = bn + wn + j * 16 + lid;
        float bb = bias[col];
#pragma unroll
        for (int i = 0; i < 4; ++i) {
#pragma unroll
            for (int r = 0; r < 4; ++r) {
                int row = bm + wm + i * 16 + quad * 4 + r;
                float v = acc[i][j][r] + bb;
                if (EPI == 2) {
                    ((float*)outp)[(size_t)row * N + col] = res[(size_t)row * N + col] + v;
                } else {
                    ((bf16*)outp)[(size_t)row * N + col] = f2b(fmaxf(v, 0.f));
                }
            }
        }
    }
}

// ---------------- 64x128 GEMM for N=768 outputs (Wo, FFN2), BK=64 -----------
template <int EPI>
__global__ __launch_bounds__(256) void gemm_ep64(const bf16* __restrict__ A,
                                                 const bf16* __restrict__ BT,
                                                 const float* __restrict__ bias,
                                                 const float* __restrict__ res,
                                                 void* __restrict__ outp,
                                                 int N, int K) {
    __shared__ bf16 As[64 * 64];
    __shared__ bf16 Bs[128 * 64];
    int bm = blockIdx.y * 64, bn = blockIdx.x * 128;
    int tid = threadIdx.x, wid = tid >> 6, lane = tid & 63, quad = lane >> 4, lid = lane & 15;
    int wm = (wid >> 1) * 32, wn = (wid & 1) * 64;
    f32x4 acc[2][4] = {};
    const bf16* Ap[2];
    const bf16* Bp[4];
#pragma unroll
    for (int it = 0; it < 2; ++it) {
        int s = tid + it * 256;
        int r = s >> 3, c = (s & 7) ^ (r & 7);
        Ap[it] = A + (size_t)(bm + r) * K + c * 8;
    }
#pragma unroll
    for (int it = 0; it < 4; ++it) {
        int s = tid + it * 256;
        int r = s >> 3, c = (s & 7) ^ (r & 7);
        Bp[it] = BT + (size_t)(bn + r) * K + c * 8;
    }
    int rdc = quad ^ (lid & 7);
    for (int k0 = 0; k0 < K; k0 += 64) {
        __syncthreads();
#pragma unroll
        for (int it = 0; it < 2; ++it)
            g2l16(Ap[it] + k0, As + (tid + it * 256) * 8);
#pragma unroll
        for (int it = 0; it < 4; ++it)
            g2l16(Bp[it] + k0, Bs + (tid + it * 256) * 8);
        __syncthreads();
#pragma unroll
        for (int kk = 0; kk < 2; ++kk) {
            int pc = rdc ^ (kk * 4);
            bf16x8 af[2], bfr[4];
#pragma unroll
            for (int i = 0; i < 2; ++i) af[i]  = *(const bf16x8*)&As[(wm + i * 16 + lid) * 64 + pc * 8];
#pragma unroll
            for (int j = 0; j < 4; ++j) bfr[j] = *(const bf16x8*)&Bs[(wn + j * 16 + lid) * 64 + pc * 8];
#pragma unroll
            for (int i = 0; i < 2; ++i)
#pragma unroll
                for (int j = 0; j < 4; ++j)
                    acc[i][j] = MFMA16(af[i], bfr[j], acc[i][j]);
        }
    }
#pragma unroll
    for (int j = 0; j < 4; ++j) {
        int col = bn + wn + j * 16 + lid;
        float bb = bias[col];
#pragma unroll
        for (int i = 0; i < 2; ++i) {
#pragma unroll
            for (int r = 0; r < 4; ++r) {
                int row = bm + wm + i * 16 + quad * 4 + r;
                float v = acc[i][j][r] + bb;
                if (EPI == 2) {
                    ((float*)outp)[(size_t)row * N + col] = res[(size_t)row * N + col] + v;
                } else {
                    ((bf16*)outp)[(size_t)row * N + col] = f2b(fmaxf(v, 0.f));
                }
            }
        }
    }
}

// ---------------- flash attention, k-chunk partials (R7 version) ------------
__global__ __launch_bounds__(256) void attn_part(const bf16* __restrict__ qb,
                                                 const bf16* __restrict__ kb,
                                                 const bf16* __restrict__ vtb,
                                                 const int* __restrict__ mask,
                                                 bf16* __restrict__ part,
                                                 float* __restrict__ lws) {
    __shared__ bf16 Ks[64 * 64];
    __shared__ bf16 VTs[64 * 64];
    __shared__ bf16 Ps[64 * 72];   // [q][k], stride 72 -> b128 reads benign
    int bh = blockIdx.y;
    int b = bh / NH, h = bh % NH;
    int q0 = blockIdx.x * 64;
    int kc = blockIdx.z;
    const bf16* Kp = kb  + (size_t)bh * SS * DK;
    const bf16* VT = vtb + (size_t)bh * DK * SS;
    int tid = threadIdx.x, wid = tid >> 6, lane = tid & 63, quad = lane >> 4, lid = lane & 15;

    int s0 = tid, s1 = tid + 256;
    int r0 = s0 >> 3, c0 = (s0 & 7) ^ (r0 & 7);
    int r1 = s1 >> 3, c1 = (s1 & 7) ^ (r1 & 7);

    // Q fragment to registers; same lane mapping serves as B-operand for S^T
    const bf16* Qrow = qb + ((size_t)bh * SS + q0 + wid * 16 + lid) * DK;
    bf16x8 qf0 = *(const bf16x8*)&Qrow[quad * 8];
    bf16x8 qf1 = *(const bf16x8*)&Qrow[32 + quad * 8];

    bf16x8 ones;
#pragma unroll
    for (int i = 0; i < 8; ++i) ones[i] = (short)0x3F80;   // bf16 1.0

    int rdc  = quad ^ (lid & 7);
    int rdc2 = rdc ^ 4;
    const int* mrow = mask + b * SS;

    f32x4 accv[4] = {};
    f32x4 accl = {};

    for (int t = kc * (SS / 64 / KCH); t < (kc + 1) * (SS / 64 / KCH); ++t) {
        int k0 = t * 64;
        __syncthreads();
        g2l16(Kp + (size_t)(k0 + r0) * DK + c0 * 8, Ks + s0 * 8);
        g2l16(Kp + (size_t)(k0 + r1) * DK + c1 * 8, Ks + s1 * 8);
        g2l16(VT + (size_t)r0 * SS + k0 + c0 * 8, VTs + s0 * 8);
        g2l16(VT + (size_t)r1 * SS + k0 + c1 * 8, VTs + s1 * 8);
        __syncthreads();

        // S^T: lane holds k = ns*16 + quad*4 + r, q = wid*16 + lid
#pragma unroll
        for (int ns = 0; ns < 4; ++ns) {
            bf16x8 kf0 = *(const bf16x8*)&Ks[(ns * 16 + lid) * 64 + rdc * 8];
            bf16x8 kf1 = *(const bf16x8*)&Ks[(ns * 16 + lid) * 64 + rdc2 * 8];
            f32x4 st = {};
            st = MFMA16(kf0, qf0, st);
            st = MFMA16(kf1, qf1, st);
            int4 mk = *(const int4*)&mrow[k0 + ns * 16 + quad * 4];
            float p0 = mk.x ? exp2f(st[0]) : 0.f;
            float p1 = mk.y ? exp2f(st[1]) : 0.f;
            float p2 = mk.z ? exp2f(st[2]) : 0.f;
            float p3 = mk.w ? exp2f(st[3]) : 0.f;
            __hip_bfloat162 h01 = __float22bfloat162_rn(make_float2(p0, p1));
            __hip_bfloat162 h23 = __float22bfloat162_rn(make_float2(p2, p3));
            uint2 pw;
            pw.x = *(unsigned int*)&h01;
            pw.y = *(unsigned int*)&h23;
            *(uint2*)&Ps[(wid * 16 + lid) * 72 + ns * 16 + quad * 4] = pw;
        }

        // P A-frags (same-wave round trip, no barrier)
        bf16x8 pa0 = *(const bf16x8*)&Ps[(wid * 16 + lid) * 72 + quad * 8];
        bf16x8 pa1 = *(const bf16x8*)&Ps[(wid * 16 + lid) * 72 + 32 + quad * 8];

        // denominator via ones-MFMA: accl[r] = sum_k P[q=wid*16+quad*4+r][k]
        accl = MFMA16(pa0, ones, accl);
        accl = MFMA16(pa1, ones, accl);

#pragma unroll
        for (int ds = 0; ds < 4; ++ds) {
            bf16x8 vf0 = *(const bf16x8*)&VTs[(ds * 16 + lid) * 64 + rdc * 8];
            bf16x8 vf1 = *(const bf16x8*)&VTs[(ds * 16 + lid) * 64 + rdc2 * 8];
            accv[ds] = MFMA16(pa0, vf0, accv[ds]);
            accv[ds] = MFMA16(pa1, vf1, accv[ds]);
        }
    }

    if (lid == 0) {
#pragma unroll
        for (int r = 0; r < 4; ++r)
            lws[((size_t)kc * (2 * NH) + bh) * SS + q0 + wid * 16 + quad * 4 + r] = accl[r];
    }

    // raw partial context (no divide)
#pragma unroll
    for (int ds = 0; ds < 4; ++ds) {
#pragma unroll
        for (int r = 0; r < 4; ++r) {
            int row = q0 + wid * 16 + quad * 4 + r;
            int col = h * DK + ds * 16 + lid;
            part[((size_t)kc * NTOK + b * SS + row) * DM + col] = f2b(accv[ds][r]);
        }
    }
}

// combine: ctx[t][c] = sum_kc part[kc][t][c] / sum_kc l[kc][bh(t,c)][q(t)]
__global__ __launch_bounds__(256) void attn_combine(const bf16* __restrict__ part,
                                                    const float* __restrict__ lws,
                                                    bf16* __restrict__ ctx) {
    int c = blockIdx.x * 256 + threadIdx.x;
    int t = blockIdx.y;
    int h = c >> 6;
    int b = t >> 11, q = t & 2047;
    int bh = b * NH + h;
    float s = 0.f, l = 0.f;
#pragma unroll
    for (int kc = 0; kc < KCH; ++kc) {
        s += b2f(part[((size_t)kc * NTOK + t) * DM + c]);
        l += lws[((size_t)kc * (2 * NH) + bh) * SS + q];
    }
    ctx[(size_t)t * DM + c] = f2b(s / l);
}

// ---------------- host launch ----------------------------------------------
extern "C" void kernel_launch(void* const* d_in, const int* in_sizes, int n_in,
                              void* d_out, int out_size, void* d_ws, size_t ws_size,
                              hipStream_t stream) {
    const float* x    = (const float*)d_in[0];
    const int*   mask = (const int*)d_in[1];
    const float* Wq   = (const float*)d_in[2];
    const float* bq   = (const float*)d_in[3];
    const float* Wk   = (const float*)d_in[4];
    const float* bk   = (const float*)d_in[5];
    const float* Wv   = (const float*)d_in[6];
    const float* bv   = (const float*)d_in[7];
    const float* Wo   = (const float*)d_in[8];
    const float* bo   = (const float*)d_in[9];
    const float* ln1a = (const float*)d_in[10];
    const float* ln1b = (const float*)d_in[11];
    const float* W1   = (const float*)d_in[12];
    const float* b1   = (const float*)d_in[13];
    const float* W2   = (const float*)d_in[14];
    const float* b2   = (const float*)d_in[15];
    const float* ln2a = (const float*)d_in[16];
    const float* ln2b = (const float*)d_in[17];
    float* out = (float*)d_out;

    char* w = (char*)d_ws;
    bf16* h   = (bf16*)w; w += (size_t)NTOK * DM * 2;
    bf16* qb  = (bf16*)w; w += (size_t)NTOK * DM * 2;
    bf16* kb  = (bf16*)w; w += (size_t)NTOK * DM * 2;
    bf16* vtb = (bf16*)w; w += (size_t)NTOK * DM * 2;
    bf16* ctx = (bf16*)w; w += (size_t)NTOK * DM * 2;
    bf16* h2  = (bf16*)w; w += (size_t)NTOK * DM * 2;
    bf16* ffa = (bf16*)w; w += (size_t)NTOK * DFF * 2;   // also attn partials (temporally disjoint)
    float* x1 = (float*)w; w += (size_t)NTOK * DM * 4;   // also attn l-partials (temporally disjoint)
    bf16* WqT = (bf16*)w; w += (size_t)DM * DM * 2;
    bf16* WkT = (bf16*)w; w += (size_t)DM * DM * 2;
    bf16* WvT = (bf16*)w; w += (size_t)DM * DM * 2;
    bf16* WoT = (bf16*)w; w += (size_t)DM * DM * 2;
    bf16* W1T = (bf16*)w; w += (size_t)DM * DFF * 2;
    bf16* W2T = (bf16*)w; w += (size_t)DM * DFF * 2;

    bf16*  part = ffa;          // KCH*NTOK*DM*2 = 24 MB == NTOK*DFF*2, exact alias
    float* lws  = x1;           // KCH*24*SS*4 = 768 KB < NTOK*DM*4

    transpose_all<<<6912, 256, 0, stream>>>(Wq, Wk, Wv, Wo, W1, W2,
                                            WqT, WkT, WvT, WoT, W1T, W2T);

    ln_fwd<<<NTOK / 4, 256, 0, stream>>>(x, ln1a, ln1b, h);
    gemm_qkv<<<dim3(18, 32), 256, 0, stream>>>(h, WqT, WkT, WvT, bq, bk, bv, qb, kb, vtb);
    attn_part<<<dim3(SS / 64, 2 * NH, KCH), 256, 0, stream>>>(qb, kb, vtb, mask, part, lws);
    attn_combine<<<dim3(DM / 256, NTOK), 256, 0, stream>>>(part, lws, ctx);
    gemm_ep64<2><<<dim3(6, 64), 256, 0, stream>>>(ctx, WoT, bo, x, (void*)x1, DM, DM);
    ln_fwd<<<NTOK / 4, 256, 0, stream>>>(x1, ln2a, ln2b, h2);
    gemm_ep<3><<<dim3(24, 32), 256, 0, stream>>>(h2, W1T, b1, nullptr, (void*)ffa, DFF, DM);
    gemm_ep64<2><<<dim3(6, 64), 256, 0, stream>>>(ffa, W2T, b2, x1, (void*)out, DM, DFF);
}

// Round 9
// 311.694 us; speedup vs baseline: 1.0079x; 1.0079x over previous
//
#include <hip/hip_runtime.h>
#include <hip/hip_bf16.h>
#include <stdint.h>

#define DM 768
#define DFF 3072
#define NH 12
#define DK 64
#define SS 2048
#define NTOK 4096   // B*S = 2*2048
#define KCH 8       // attention k-chunks: 32x24x8 = 6144 blocks = 6/CU resident

typedef __hip_bfloat16 bf16;
typedef short bf16x8 __attribute__((ext_vector_type(8)));
typedef float f32x4 __attribute__((ext_vector_type(4)));

#define MFMA16(a, b, c) __builtin_amdgcn_mfma_f32_16x16x32_bf16((a), (b), (c), 0, 0, 0)

// 0.125 (1/sqrt(Dk)) * log2(e), folded into the Q projection so attention uses exp2
#define QSCALE 0.18033688011112042f

#if __has_builtin(__builtin_amdgcn_exp2f)
#define EXP2F(x) __builtin_amdgcn_exp2f(x)   // raw v_exp_f32, no libm fixup
#else
#define EXP2F(x) exp2f(x)
#endif

static __device__ __forceinline__ bf16 f2b(float f) { return __float2bfloat16(f); }
static __device__ __forceinline__ unsigned short f2b_bits(float f) {
    bf16 h = __float2bfloat16(f);
    return *reinterpret_cast<unsigned short*>(&h);
}
static __device__ __forceinline__ float b2f(bf16 h) { return __bfloat162float(h); }

// async 16B global->LDS DMA. LDS dest must be wave-uniform base + lane*16.
static __device__ __forceinline__ void g2l16(const void* g, void* l) {
    __builtin_amdgcn_global_load_lds(
        (const __attribute__((address_space(1))) unsigned int*)g,
        (__attribute__((address_space(3))) unsigned int*)(uintptr_t)l,
        16, 0, 0);
}

// ---------------- all 6 weight transposes (fp32->bf16, [K,N]->[N,K]) --------
__global__ __launch_bounds__(256) void transpose_all(const float* Wq, const float* Wk,
                                                     const float* Wv, const float* Wo,
                                                     const float* W1, const float* W2,
                                                     bf16* WqT, bf16* WkT, bf16* WvT,
                                                     bf16* WoT, bf16* W1T, bf16* W2T) {
    __shared__ float tile[32][33];
    int id = blockIdx.x;
    const float* W; bf16* WT; int K, N, n0, k0;
    if (id < 2304) {            // Wq/Wk/Wv/Wo: 768x768, 24x24 blocks each
        int z = id / 576, r = id % 576;
        W  = (z == 0) ? Wq : (z == 1) ? Wk : (z == 2) ? Wv : Wo;
        WT = (z == 0) ? WqT : (z == 1) ? WkT : (z == 2) ? WvT : WoT;
        K = 768; N = 768; n0 = (r % 24) * 32; k0 = (r / 24) * 32;
    } else if (id < 4608) {     // W1: [768,3072] -> [3072,768]
        int r = id - 2304; W = W1; WT = W1T;
        K = 768; N = 3072; n0 = (r % 96) * 32; k0 = (r / 96) * 32;
    } else {                    // W2: [3072,768] -> [768,3072]
        int r = id - 4608; W = W2; WT = W2T;
        K = 3072; N = 768; n0 = (r % 24) * 32; k0 = (r / 24) * 32;
    }
    int tx = threadIdx.x & 31, ty = threadIdx.x >> 5;
#pragma unroll
    for (int r = ty; r < 32; r += 8)
        tile[r][tx] = W[(size_t)(k0 + r) * N + n0 + tx];
    __syncthreads();
#pragma unroll
    for (int r = ty; r < 32; r += 8)
        WT[(size_t)(n0 + r) * K + k0 + tx] = f2b(tile[tx][r]);
}

// ---------------- LayerNorm (unbiased var, eps on std) --------
__global__ __launch_bounds__(256) void ln_fwd(const float* __restrict__ x,
                                              const float* __restrict__ g,
                                              const float* __restrict__ be,
                                              bf16* __restrict__ out) {
    int wid = threadIdx.x >> 6, lane = threadIdx.x & 63;
    int row = blockIdx.x * 4 + wid;
    const float* xr = x + (size_t)row * DM;
    float v[12];
    float s = 0.f;
#pragma unroll
    for (int i = 0; i < 12; ++i) { v[i] = xr[lane + i * 64]; s += v[i]; }
#pragma unroll
    for (int off = 32; off >= 1; off >>= 1) s += __shfl_xor(s, off);
    float mean = s * (1.f / 768.f);
    float s2 = 0.f;
#pragma unroll
    for (int i = 0; i < 12; ++i) { float d = v[i] - mean; s2 += d * d; }
#pragma unroll
    for (int off = 32; off >= 1; off >>= 1) s2 += __shfl_xor(s2, off);
    float rstd = 1.f / (sqrtf(s2 * (1.f / 767.f)) + 1e-6f);
    bf16* orow = out + (size_t)row * DM;
#pragma unroll
    for (int i = 0; i < 12; ++i) {
        int c = lane + i * 64;
        orow[c] = f2b(g[c] * (v[i] - mean) * rstd + be[c]);
    }
}

// ---------------- 128x128 GEMM core, BK=32, dbuf, prefetch-after-barrier -----
// (R7-proven best) 16B chunk c of row r at phys chunk c ^ ((r>>1)&3).
__device__ __forceinline__ void gemm_core(const bf16* __restrict__ A,
                                          const bf16* __restrict__ BT,
                                          int K, int bm, int bn,
                                          bf16* As, bf16* Bs,   // each 2*128*32
                                          f32x4 acc[4][4]) {
    int tid = threadIdx.x;
    int lane = tid & 63, quad = lane >> 4, lid = lane & 15;
    int wid = tid >> 6;
    int wm = (wid >> 1) * 64, wn = (wid & 1) * 64;
    int s0 = tid, s1 = tid + 256;
    int r0 = s0 >> 2, c0 = (s0 & 3) ^ ((r0 >> 1) & 3);
    int r1 = s1 >> 2, c1 = (s1 & 3) ^ ((r1 >> 1) & 3);
    const bf16* A0 = A + (size_t)(bm + r0) * K + c0 * 8;
    const bf16* A1 = A + (size_t)(bm + r1) * K + c1 * 8;
    const bf16* B0 = BT + (size_t)(bn + r0) * K + c0 * 8;
    const bf16* B1 = BT + (size_t)(bn + r1) * K + c1 * 8;
    int rdc = quad ^ ((lid >> 1) & 3);
    g2l16(A0, As + s0 * 8);
    g2l16(B0, Bs + s0 * 8);
    g2l16(A1, As + s1 * 8);
    g2l16(B1, Bs + s1 * 8);
    for (int k0 = 0; k0 < K; k0 += 32) {
        __syncthreads();
        int cur = (k0 >> 5) & 1;
        if (k0 + 32 < K) {
            int nb = (cur ^ 1) * 4096;
            g2l16(A0 + k0 + 32, As + nb + s0 * 8);
            g2l16(B0 + k0 + 32, Bs + nb + s0 * 8);
            g2l16(A1 + k0 + 32, As + nb + s1 * 8);
            g2l16(B1 + k0 + 32, Bs + nb + s1 * 8);
        }
        const bf16* Ac = As + cur * 4096;
        const bf16* Bc = Bs + cur * 4096;
        bf16x8 af[4], bfr[4];
#pragma unroll
        for (int i = 0; i < 4; ++i) af[i]  = *(const bf16x8*)&Ac[(wm + i * 16 + lid) * 32 + rdc * 8];
#pragma unroll
        for (int j = 0; j < 4; ++j) bfr[j] = *(const bf16x8*)&Bc[(wn + j * 16 + lid) * 32 + rdc * 8];
#pragma unroll
        for (int i = 0; i < 4; ++i)
#pragma unroll
            for (int j = 0; j < 4; ++j)
                acc[i][j] = MFMA16(af[i], bfr[j], acc[i][j]);
    }
}

// ---------------- fused QKV projection -------------------------------------
__global__ __launch_bounds__(256) void gemm_qkv(const bf16* __restrict__ A,
                                                const bf16* __restrict__ WqT,
                                                const bf16* __restrict__ WkT,
                                                const bf16* __restrict__ WvT,
                                                const float* __restrict__ bq,
                                                const float* __restrict__ bk,
                                                const float* __restrict__ bv,
                                                bf16* __restrict__ qb,
                                                bf16* __restrict__ kb,
                                                bf16* __restrict__ vtb) {
    __shared__ bf16 As[2 * 128 * 32];
    __shared__ bf16 Bs[2 * 128 * 32];
    int which = blockIdx.x / 6;
    int bn = (blockIdx.x % 6) * 128;
    int bm = blockIdx.y * 128;
    const bf16* BT = (which == 0) ? WqT : (which == 1) ? WkT : WvT;
    const float* bias = (which == 0) ? bq : (which == 1) ? bk : bv;
    f32x4 acc[4][4] = {};
    gemm_core(A, BT, DM, bm, bn, As, Bs, acc);

    int tid = threadIdx.x, wid = tid >> 6, lane = tid & 63, quad = lane >> 4, lid = lane & 15;
    int wm = (wid >> 1) * 64, wn = (wid & 1) * 64;
    float sc = (which == 0) ? QSCALE : 1.f;   // fold softmax scale+log2e into Q
#pragma unroll
    for (int j = 0; j < 4; ++j) {
        int col = bn + wn + j * 16 + lid;
        float bb = bias[col];
        int hh = col >> 6, d = col & 63;
#pragma unroll
        for (int i = 0; i < 4; ++i) {
            int rowbase = bm + wm + i * 16 + quad * 4;
            int b = rowbase >> 11;
            int s0 = rowbase & 2047;
            if (which == 2) {
                ushort4 pk;
                pk.x = f2b_bits(acc[i][j][0] + bb);
                pk.y = f2b_bits(acc[i][j][1] + bb);
                pk.z = f2b_bits(acc[i][j][2] + bb);
                pk.w = f2b_bits(acc[i][j][3] + bb);
                *(ushort4*)&vtb[(((size_t)b * NH + hh) * DK + d) * SS + s0] = pk;
            } else {
                bf16* dst = which ? kb : qb;
#pragma unroll
                for (int r = 0; r < 4; ++r)
                    dst[(((size_t)b * NH + hh) * SS + (s0 + r)) * DK + d] = f2b((acc[i][j][r] + bb) * sc);
            }
        }
    }
}

// ---------------- 128x128 GEMM with epilogues (FFN1) ---------------
template <int EPI>
__global__ __launch_bounds__(256) void gemm_ep(const bf16* __restrict__ A,
                                               const bf16* __restrict__ BT,
                                               const float* __restrict__ bias,
                                               const float* __restrict__ res,
                                               void* __restrict__ outp,
                                               int N, int K) {
    __shared__ bf16 As[2 * 128 * 32];
    __shared__ bf16 Bs[2 * 128 * 32];
    int bm = blockIdx.y * 128, bn = blockIdx.x * 128;
    f32x4 acc[4][4] = {};
    gemm_core(A, BT, K, bm, bn, As, Bs, acc);

    int tid = threadIdx.x, wid = tid >> 6, lane = tid & 63, quad = lane >> 4, lid = lane & 15;
    int wm = (wid >> 1) * 64, wn = (wid & 1) * 64;
#pragma unroll
    for (int j = 0; j < 4; ++j) {
        int col = bn + wn + j * 16 + lid;
        float bb = bias[col];
#pragma unroll
        for (int i = 0; i < 4; ++i) {
#pragma unroll
            for (int r = 0; r < 4; ++r) {
                int row = bm + wm + i * 16 + quad * 4 + r;
                float v = acc[i][j][r] + bb;
                if (EPI == 2) {
                    ((float*)outp)[(size_t)row * N + col] = res[(size_t)row * N + col] + v;
                } else {
                    ((bf16*)outp)[(size_t)row * N + col] = f2b(fmaxf(v, 0.f));
                }
            }
        }
    }
}

// ---------------- 64x128 GEMM for N=768 outputs (Wo, FFN2), dbuf ------------
template <int EPI>
__global__ __launch_bounds__(256) void gemm_ep64(const bf16* __restrict__ A,
                                                 const bf16* __restrict__ BT,
                                                 const float* __restrict__ bias,
                                                 const float* __restrict__ res,
                                                 void* __restrict__ outp,
                                                 int N, int K) {
    __shared__ bf16 As[2 * 64 * 32];
    __shared__ bf16 Bs[2 * 128 * 32];
    int bm = blockIdx.y * 64, bn = blockIdx.x * 128;
    int tid = threadIdx.x, wid = tid >> 6, lane = tid & 63, quad = lane >> 4, lid = lane & 15;
    int wm = (wid >> 1) * 32, wn = (wid & 1) * 64;
    f32x4 acc[2][4] = {};
    int ra = tid >> 2, ca = (tid & 3) ^ ((ra >> 1) & 3);
    int s0 = tid, s1 = tid + 256;
    int rb0 = s0 >> 2, cb0 = (s0 & 3) ^ ((rb0 >> 1) & 3);
    int rb1 = s1 >> 2, cb1 = (s1 & 3) ^ ((rb1 >> 1) & 3);
    const bf16* Ap = A + (size_t)(bm + ra) * K + ca * 8;
    const bf16* B0 = BT + (size_t)(bn + rb0) * K + cb0 * 8;
    const bf16* B1 = BT + (size_t)(bn + rb1) * K + cb1 * 8;
    int rdc = quad ^ ((lid >> 1) & 3);
    g2l16(Ap, As + tid * 8);
    g2l16(B0, Bs + s0 * 8);
    g2l16(B1, Bs + s1 * 8);
    for (int k0 = 0; k0 < K; k0 += 32) {
        __syncthreads();
        int cur = (k0 >> 5) & 1;
        if (k0 + 32 < K) {
            g2l16(Ap + k0 + 32, As + (cur ^ 1) * 2048 + tid * 8);
            g2l16(B0 + k0 + 32, Bs + (cur ^ 1) * 4096 + s0 * 8);
            g2l16(B1 + k0 + 32, Bs + (cur ^ 1) * 4096 + s1 * 8);
        }
        const bf16* Ac = As + cur * 2048;
        const bf16* Bc = Bs + cur * 4096;
        bf16x8 af[2], bfr[4];
#pragma unroll
        for (int i = 0; i < 2; ++i) af[i]  = *(const bf16x8*)&Ac[(wm + i * 16 + lid) * 32 + rdc * 8];
#pragma unroll
        for (int j = 0; j < 4; ++j) bfr[j] = *(const bf16x8*)&Bc[(wn + j * 16 + lid) * 32 + rdc * 8];
#pragma unroll
        for (int i = 0; i < 2; ++i)
#pragma unroll
            for (int j = 0; j < 4; ++j)
                acc[i][j] = MFMA16(af[i], bfr[j], acc[i][j]);
    }
#pragma unroll
    for (int j = 0; j < 4; ++j) {
        int col = bn + wn + j * 16 + lid;
        float bb = bias[col];
#pragma unroll
        for (int i = 0; i < 2; ++i) {
#pragma unroll
            for (int r = 0; r < 4; ++r) {
                int row = bm + wm + i * 16 + quad * 4 + r;
                float v = acc[i][j][r] + bb;
                if (EPI == 2) {
                    ((float*)outp)[(size_t)row * N + col] = res[(size_t)row * N + col] + v;
                } else {
                    ((bf16*)outp)[(size_t)row * N + col] = f2b(fmaxf(v, 0.f));
                }
            }
        }
    }
}

// ---------------- flash attention, k-chunk partials (R7 body, KCH=8) --------
// grid (SS/64, B*NH, KCH) = 6144 blocks = 6 resident/CU (LDS 25.6KB).
__global__ __launch_bounds__(256) void attn_part(const bf16* __restrict__ qb,
                                                 const bf16* __restrict__ kb,
                                                 const bf16* __restrict__ vtb,
                                                 const int* __restrict__ mask,
                                                 bf16* __restrict__ part,
                                                 float* __restrict__ lws) {
    __shared__ bf16 Ks[64 * 64];
    __shared__ bf16 VTs[64 * 64];
    __shared__ bf16 Ps[64 * 72];   // [q][k], stride 72 -> b128 reads benign
    int bh = blockIdx.y;
    int b = bh / NH, h = bh % NH;
    int q0 = blockIdx.x * 64;
    int kc = blockIdx.z;
    const bf16* Kp = kb  + (size_t)bh * SS * DK;
    const bf16* VT = vtb + (size_t)bh * DK * SS;
    int tid = threadIdx.x, wid = tid >> 6, lane = tid & 63, quad = lane >> 4, lid = lane & 15;

    int s0 = tid, s1 = tid + 256;
    int r0 = s0 >> 3, c0 = (s0 & 7) ^ (r0 & 7);
    int r1 = s1 >> 3, c1 = (s1 & 7) ^ (r1 & 7);

    // Q fragment to registers; same lane mapping serves as B-operand for S^T
    const bf16* Qrow = qb + ((size_t)bh * SS + q0 + wid * 16 + lid) * DK;
    bf16x8 qf0 = *(const bf16x8*)&Qrow[quad * 8];
    bf16x8 qf1 = *(const bf16x8*)&Qrow[32 + quad * 8];

    bf16x8 ones;
#pragma unroll
    for (int i = 0; i < 8; ++i) ones[i] = (short)0x3F80;   // bf16 1.0

    int rdc  = quad ^ (lid & 7);
    int rdc2 = rdc ^ 4;
    const int* mrow = mask + b * SS;

    f32x4 accv[4] = {};
    f32x4 accl = {};

    for (int t = kc * (SS / 64 / KCH); t < (kc + 1) * (SS / 64 / KCH); ++t) {
        int k0 = t * 64;
        __syncthreads();
        g2l16(Kp + (size_t)(k0 + r0) * DK + c0 * 8, Ks + s0 * 8);
        g2l16(Kp + (size_t)(k0 + r1) * DK + c1 * 8, Ks + s1 * 8);
        g2l16(VT + (size_t)r0 * SS + k0 + c0 * 8, VTs + s0 * 8);
        g2l16(VT + (size_t)r1 * SS + k0 + c1 * 8, VTs + s1 * 8);
        __syncthreads();

        // S^T: lane holds k = ns*16 + quad*4 + r, q = wid*16 + lid
#pragma unroll
        for (int ns = 0; ns < 4; ++ns) {
            bf16x8 kf0 = *(const bf16x8*)&Ks[(ns * 16 + lid) * 64 + rdc * 8];
            bf16x8 kf1 = *(const bf16x8*)&Ks[(ns * 16 + lid) * 64 + rdc2 * 8];
            f32x4 st = {};
            st = MFMA16(kf0, qf0, st);
            st = MFMA16(kf1, qf1, st);
            int4 mk = *(const int4*)&mrow[k0 + ns * 16 + quad * 4];
            float p0 = mk.x ? EXP2F(st[0]) : 0.f;
            float p1 = mk.y ? EXP2F(st[1]) : 0.f;
            float p2 = mk.z ? EXP2F(st[2]) : 0.f;
            float p3 = mk.w ? EXP2F(st[3]) : 0.f;
            __hip_bfloat162 h01 = __float22bfloat162_rn(make_float2(p0, p1));
            __hip_bfloat162 h23 = __float22bfloat162_rn(make_float2(p2, p3));
            uint2 pw;
            pw.x = *(unsigned int*)&h01;
            pw.y = *(unsigned int*)&h23;
            *(uint2*)&Ps[(wid * 16 + lid) * 72 + ns * 16 + quad * 4] = pw;
        }

        // P A-frags (same-wave round trip, no barrier)
        bf16x8 pa0 = *(const bf16x8*)&Ps[(wid * 16 + lid) * 72 + quad * 8];
        bf16x8 pa1 = *(const bf16x8*)&Ps[(wid * 16 + lid) * 72 + 32 + quad * 8];

        // denominator via ones-MFMA: accl[r] = sum_k P[q=wid*16+quad*4+r][k]
        accl = MFMA16(pa0, ones, accl);
        accl = MFMA16(pa1, ones, accl);

#pragma unroll
        for (int ds = 0; ds < 4; ++ds) {
            bf16x8 vf0 = *(const bf16x8*)&VTs[(ds * 16 + lid) * 64 + rdc * 8];
            bf16x8 vf1 = *(const bf16x8*)&VTs[(ds * 16 + lid) * 64 + rdc2 * 8];
            accv[ds] = MFMA16(pa0, vf0, accv[ds]);
            accv[ds] = MFMA16(pa1, vf1, accv[ds]);
        }
    }

    if (lid == 0) {
#pragma unroll
        for (int r = 0; r < 4; ++r)
            lws[((size_t)kc * (2 * NH) + bh) * SS + q0 + wid * 16 + quad * 4 + r] = accl[r];
    }

    // raw partial context (no divide)
#pragma unroll
    for (int ds = 0; ds < 4; ++ds) {
#pragma unroll
        for (int r = 0; r < 4; ++r) {
            int row = q0 + wid * 16 + quad * 4 + r;
            int col = h * DK + ds * 16 + lid;
            part[((size_t)kc * NTOK + b * SS + row) * DM + col] = f2b(accv[ds][r]);
        }
    }
}

// combine: ctx[t][c] = sum_kc part[kc][t][c] / sum_kc l[kc][bh(t,c)][q(t)]
__global__ __launch_bounds__(256) void attn_combine(const bf16* __restrict__ part,
                                                    const float* __restrict__ lws,
                                                    bf16* __restrict__ ctx) {
    int c = blockIdx.x * 256 + threadIdx.x;
    int t = blockIdx.y;
    int h = c >> 6;
    int b = t >> 11, q = t & 2047;
    int bh = b * NH + h;
    float s = 0.f, l = 0.f;
#pragma unroll
    for (int kc = 0; kc < KCH; ++kc) {
        s += b2f(part[((size_t)kc * NTOK + t) * DM + c]);
        l += lws[((size_t)kc * (2 * NH) + bh) * SS + q];
    }
    ctx[(size_t)t * DM + c] = f2b(s / l);
}

// ---------------- host launch ----------------------------------------------
extern "C" void kernel_launch(void* const* d_in, const int* in_sizes, int n_in,
                              void* d_out, int out_size, void* d_ws, size_t ws_size,
                              hipStream_t stream) {
    const float* x    = (const float*)d_in[0];
    const int*   mask = (const int*)d_in[1];
    const float* Wq   = (const float*)d_in[2];
    const float* bq   = (const float*)d_in[3];
    const float* Wk   = (const float*)d_in[4];
    const float* bk   = (const float*)d_in[5];
    const float* Wv   = (const float*)d_in[6];
    const float* bv   = (const float*)d_in[7];
    const float* Wo   = (const float*)d_in[8];
    const float* bo   = (const float*)d_in[9];
    const float* ln1a = (const float*)d_in[10];
    const float* ln1b = (const float*)d_in[11];
    const float* W1   = (const float*)d_in[12];
    const float* b1   = (const float*)d_in[13];
    const float* W2   = (const float*)d_in[14];
    const float* b2   = (const float*)d_in[15];
    const float* ln2a = (const float*)d_in[16];
    const float* ln2b = (const float*)d_in[17];
    float* out = (float*)d_out;

    // Layout: live-through-attention buffers first, then the part-alias region
    // [h, h2, ffa, x1] whose total is exactly KCH*NTOK*DM*2 = 48 MB (KCH=8).
    char* w = (char*)d_ws;
    bf16* qb  = (bf16*)w; w += (size_t)NTOK * DM * 2;
    bf16* kb  = (bf16*)w; w += (size_t)NTOK * DM * 2;
    bf16* vtb = (bf16*)w; w += (size_t)NTOK * DM * 2;
    bf16* ctx = (bf16*)w; w += (size_t)NTOK * DM * 2;
    char* alias0 = w;
    bf16* h   = (bf16*)w; w += (size_t)NTOK * DM * 2;   // 1 unit
    bf16* h2  = (bf16*)w; w += (size_t)NTOK * DM * 2;   // 1 unit
    bf16* ffa = (bf16*)w; w += (size_t)NTOK * DFF * 2;  // 4 units
    float* x1 = (float*)w; w += (size_t)NTOK * DM * 4;  // 2 units -> total 8
    bf16* WqT = (bf16*)w; w += (size_t)DM * DM * 2;
    bf16* WkT = (bf16*)w; w += (size_t)DM * DM * 2;
    bf16* WvT = (bf16*)w; w += (size_t)DM * DM * 2;
    bf16* WoT = (bf16*)w; w += (size_t)DM * DM * 2;
    bf16* W1T = (bf16*)w; w += (size_t)DM * DFF * 2;
    bf16* W2T = (bf16*)w; w += (size_t)DM * DFF * 2;
    float* lws = (float*)w; w += (size_t)KCH * 2 * NH * SS * 4;

    bf16* part = (bf16*)alias0;   // KCH*NTOK*DM*2, used only during attn phase

    transpose_all<<<6912, 256, 0, stream>>>(Wq, Wk, Wv, Wo, W1, W2,
                                            WqT, WkT, WvT, WoT, W1T, W2T);

    ln_fwd<<<NTOK / 4, 256, 0, stream>>>(x, ln1a, ln1b, h);
    gemm_qkv<<<dim3(18, 32), 256, 0, stream>>>(h, WqT, WkT, WvT, bq, bk, bv, qb, kb, vtb);
    attn_part<<<dim3(SS / 64, 2 * NH, KCH), 256, 0, stream>>>(qb, kb, vtb, mask, part, lws);
    attn_combine<<<dim3(DM / 256, NTOK), 256, 0, stream>>>(part, lws, ctx);
    gemm_ep64<2><<<dim3(6, 64), 256, 0, stream>>>(ctx, WoT, bo, x, (void*)x1, DM, DM);
    ln_fwd<<<NTOK / 4, 256, 0, stream>>>(x1, ln2a, ln2b, h2);
    gemm_ep<3><<<dim3(24, 32), 256, 0, stream>>>(h2, W1T, b1, nullptr, (void*)ffa, DFF, DM);
    gemm_ep64<2><<<dim3(6, 64), 256, 0, stream>>>(ffa, W2T, b2, x1, (void*)out, DM, DFF);
}

// Round 10
// 296.130 us; speedup vs baseline: 1.0609x; 1.0526x over previous
//
#include <hip/hip_runtime.h>
#include <hip/hip_bf16.h>
#include <stdint.h>

#define DM 768
#define DFF 3072
#define NH 12
#define DK 64
#define SS 2048
#define NTOK 4096   // B*S = 2*2048
#define KCH 2       // attention k-chunks: 32x24x2 = 1536 blocks = exactly 6/CU

typedef __hip_bfloat16 bf16;
typedef short bf16x8 __attribute__((ext_vector_type(8)));
typedef float f32x4 __attribute__((ext_vector_type(4)));

#define MFMA16(a, b, c) __builtin_amdgcn_mfma_f32_16x16x32_bf16((a), (b), (c), 0, 0, 0)

// 0.125 (1/sqrt(Dk)) * log2(e), folded into the Q projection so attention uses exp2
#define QSCALE 0.18033688011112042f

#if __has_builtin(__builtin_amdgcn_exp2f)
#define EXP2F(x) __builtin_amdgcn_exp2f(x)   // raw v_exp_f32, no libm fixup
#else
#define EXP2F(x) exp2f(x)
#endif

static __device__ __forceinline__ bf16 f2b(float f) { return __float2bfloat16(f); }
static __device__ __forceinline__ unsigned short f2b_bits(float f) {
    bf16 h = __float2bfloat16(f);
    return *reinterpret_cast<unsigned short*>(&h);
}
static __device__ __forceinline__ float b2f(bf16 h) { return __bfloat162float(h); }

// async 16B global->LDS DMA. LDS dest must be wave-uniform base + lane*16.
static __device__ __forceinline__ void g2l16(const void* g, void* l) {
    __builtin_amdgcn_global_load_lds(
        (const __attribute__((address_space(1))) unsigned int*)g,
        (__attribute__((address_space(3))) unsigned int*)(uintptr_t)l,
        16, 0, 0);
}

// ---------------- all 6 weight transposes (fp32->bf16, [K,N]->[N,K]) --------
__global__ __launch_bounds__(256) void transpose_all(const float* Wq, const float* Wk,
                                                     const float* Wv, const float* Wo,
                                                     const float* W1, const float* W2,
                                                     bf16* WqT, bf16* WkT, bf16* WvT,
                                                     bf16* WoT, bf16* W1T, bf16* W2T) {
    __shared__ float tile[32][33];
    int id = blockIdx.x;
    const float* W; bf16* WT; int K, N, n0, k0;
    if (id < 2304) {            // Wq/Wk/Wv/Wo: 768x768, 24x24 blocks each
        int z = id / 576, r = id % 576;
        W  = (z == 0) ? Wq : (z == 1) ? Wk : (z == 2) ? Wv : Wo;
        WT = (z == 0) ? WqT : (z == 1) ? WkT : (z == 2) ? WvT : WoT;
        K = 768; N = 768; n0 = (r % 24) * 32; k0 = (r / 24) * 32;
    } else if (id < 4608) {     // W1: [768,3072] -> [3072,768]
        int r = id - 2304; W = W1; WT = W1T;
        K = 768; N = 3072; n0 = (r % 96) * 32; k0 = (r / 96) * 32;
    } else {                    // W2: [3072,768] -> [768,3072]
        int r = id - 4608; W = W2; WT = W2T;
        K = 3072; N = 768; n0 = (r % 24) * 32; k0 = (r / 24) * 32;
    }
    int tx = threadIdx.x & 31, ty = threadIdx.x >> 5;
#pragma unroll
    for (int r = ty; r < 32; r += 8)
        tile[r][tx] = W[(size_t)(k0 + r) * N + n0 + tx];
    __syncthreads();
#pragma unroll
    for (int r = ty; r < 32; r += 8)
        WT[(size_t)(n0 + r) * K + k0 + tx] = f2b(tile[tx][r]);
}

// ---------------- LayerNorm (unbiased var, eps on std) --------
__global__ __launch_bounds__(256) void ln_fwd(const float* __restrict__ x,
                                              const float* __restrict__ g,
                                              const float* __restrict__ be,
                                              bf16* __restrict__ out) {
    int wid = threadIdx.x >> 6, lane = threadIdx.x & 63;
    int row = blockIdx.x * 4 + wid;
    const float* xr = x + (size_t)row * DM;
    float v[12];
    float s = 0.f;
#pragma unroll
    for (int i = 0; i < 12; ++i) { v[i] = xr[lane + i * 64]; s += v[i]; }
#pragma unroll
    for (int off = 32; off >= 1; off >>= 1) s += __shfl_xor(s, off);
    float mean = s * (1.f / 768.f);
    float s2 = 0.f;
#pragma unroll
    for (int i = 0; i < 12; ++i) { float d = v[i] - mean; s2 += d * d; }
#pragma unroll
    for (int off = 32; off >= 1; off >>= 1) s2 += __shfl_xor(s2, off);
    float rstd = 1.f / (sqrtf(s2 * (1.f / 767.f)) + 1e-6f);
    bf16* orow = out + (size_t)row * DM;
#pragma unroll
    for (int i = 0; i < 12; ++i) {
        int c = lane + i * 64;
        orow[c] = f2b(g[c] * (v[i] - mean) * rstd + be[c]);
    }
}

// ---------------- 128x128 GEMM core, BK=32, dbuf, prefetch-after-barrier -----
// (R7-proven best) 16B chunk c of row r at phys chunk c ^ ((r>>1)&3).
__device__ __forceinline__ void gemm_core(const bf16* __restrict__ A,
                                          const bf16* __restrict__ BT,
                                          int K, int bm, int bn,
                                          bf16* As, bf16* Bs,   // each 2*128*32
                                          f32x4 acc[4][4]) {
    int tid = threadIdx.x;
    int lane = tid & 63, quad = lane >> 4, lid = lane & 15;
    int wid = tid >> 6;
    int wm = (wid >> 1) * 64, wn = (wid & 1) * 64;
    int s0 = tid, s1 = tid + 256;
    int r0 = s0 >> 2, c0 = (s0 & 3) ^ ((r0 >> 1) & 3);
    int r1 = s1 >> 2, c1 = (s1 & 3) ^ ((r1 >> 1) & 3);
    const bf16* A0 = A + (size_t)(bm + r0) * K + c0 * 8;
    const bf16* A1 = A + (size_t)(bm + r1) * K + c1 * 8;
    const bf16* B0 = BT + (size_t)(bn + r0) * K + c0 * 8;
    const bf16* B1 = BT + (size_t)(bn + r1) * K + c1 * 8;
    int rdc = quad ^ ((lid >> 1) & 3);
    g2l16(A0, As + s0 * 8);
    g2l16(B0, Bs + s0 * 8);
    g2l16(A1, As + s1 * 8);
    g2l16(B1, Bs + s1 * 8);
    for (int k0 = 0; k0 < K; k0 += 32) {
        __syncthreads();
        int cur = (k0 >> 5) & 1;
        if (k0 + 32 < K) {
            int nb = (cur ^ 1) * 4096;
            g2l16(A0 + k0 + 32, As + nb + s0 * 8);
            g2l16(B0 + k0 + 32, Bs + nb + s0 * 8);
            g2l16(A1 + k0 + 32, As + nb + s1 * 8);
            g2l16(B1 + k0 + 32, Bs + nb + s1 * 8);
        }
        const bf16* Ac = As + cur * 4096;
        const bf16* Bc = Bs + cur * 4096;
        bf16x8 af[4], bfr[4];
#pragma unroll
        for (int i = 0; i < 4; ++i) af[i]  = *(const bf16x8*)&Ac[(wm + i * 16 + lid) * 32 + rdc * 8];
#pragma unroll
        for (int j = 0; j < 4; ++j) bfr[j] = *(const bf16x8*)&Bc[(wn + j * 16 + lid) * 32 + rdc * 8];
#pragma unroll
        for (int i = 0; i < 4; ++i)
#pragma unroll
            for (int j = 0; j < 4; ++j)
                acc[i][j] = MFMA16(af[i], bfr[j], acc[i][j]);
    }
}

// ---------------- fused QKV projection -------------------------------------
__global__ __launch_bounds__(256) void gemm_qkv(const bf16* __restrict__ A,
                                                const bf16* __restrict__ WqT,
                                                const bf16* __restrict__ WkT,
                                                const bf16* __restrict__ WvT,
                                                const float* __restrict__ bq,
                                                const float* __restrict__ bk,
                                                const float* __restrict__ bv,
                                                bf16* __restrict__ qb,
                                                bf16* __restrict__ kb,
                                                bf16* __restrict__ vtb) {
    __shared__ bf16 As[2 * 128 * 32];
    __shared__ bf16 Bs[2 * 128 * 32];
    int which = blockIdx.x / 6;
    int bn = (blockIdx.x % 6) * 128;
    int bm = blockIdx.y * 128;
    const bf16* BT = (which == 0) ? WqT : (which == 1) ? WkT : WvT;
    const float* bias = (which == 0) ? bq : (which == 1) ? bk : bv;
    f32x4 acc[4][4] = {};
    gemm_core(A, BT, DM, bm, bn, As, Bs, acc);

    int tid = threadIdx.x, wid = tid >> 6, lane = tid & 63, quad = lane >> 4, lid = lane & 15;
    int wm = (wid >> 1) * 64, wn = (wid & 1) * 64;
    float sc = (which == 0) ? QSCALE : 1.f;   // fold softmax scale+log2e into Q
#pragma unroll
    for (int j = 0; j < 4; ++j) {
        int col = bn + wn + j * 16 + lid;
        float bb = bias[col];
        int hh = col >> 6, d = col & 63;
#pragma unroll
        for (int i = 0; i < 4; ++i) {
            int rowbase = bm + wm + i * 16 + quad * 4;
            int b = rowbase >> 11;
            int s0 = rowbase & 2047;
            if (which == 2) {
                ushort4 pk;
                pk.x = f2b_bits(acc[i][j][0] + bb);
                pk.y = f2b_bits(acc[i][j][1] + bb);
                pk.z = f2b_bits(acc[i][j][2] + bb);
                pk.w = f2b_bits(acc[i][j][3] + bb);
                *(ushort4*)&vtb[(((size_t)b * NH + hh) * DK + d) * SS + s0] = pk;
            } else {
                bf16* dst = which ? kb : qb;
#pragma unroll
                for (int r = 0; r < 4; ++r)
                    dst[(((size_t)b * NH + hh) * SS + (s0 + r)) * DK + d] = f2b((acc[i][j][r] + bb) * sc);
            }
        }
    }
}

// ---------------- 128x128 GEMM with epilogues (FFN1) ---------------
template <int EPI>
__global__ __launch_bounds__(256) void gemm_ep(const bf16* __restrict__ A,
                                               const bf16* __restrict__ BT,
                                               const float* __restrict__ bias,
                                               const float* __restrict__ res,
                                               void* __restrict__ outp,
                                               int N, int K) {
    __shared__ bf16 As[2 * 128 * 32];
    __shared__ bf16 Bs[2 * 128 * 32];
    int bm = blockIdx.y * 128, bn = blockIdx.x * 128;
    f32x4 acc[4][4] = {};
    gemm_core(A, BT, K, bm, bn, As, Bs, acc);

    int tid = threadIdx.x, wid = tid >> 6, lane = tid & 63, quad = lane >> 4, lid = lane & 15;
    int wm = (wid >> 1) * 64, wn = (wid & 1) * 64;
#pragma unroll
    for (int j = 0; j < 4; ++j) {
        int col = bn + wn + j * 16 + lid;
        float bb = bias[col];
#pragma unroll
        for (int i = 0; i < 4; ++i) {
#pragma unroll
            for (int r = 0; r < 4; ++r) {
                int row = bm + wm + i * 16 + quad * 4 + r;
                float v = acc[i][j][r] + bb;
                if (EPI == 2) {
                    ((float*)outp)[(size_t)row * N + col] = res[(size_t)row * N + col] + v;
                } else {
                    ((bf16*)outp)[(size_t)row * N + col] = f2b(fmaxf(v, 0.f));
                }
            }
        }
    }
}

// ---------------- 64x128 GEMM for N=768 outputs (Wo, FFN2), dbuf ------------
template <int EPI>
__global__ __launch_bounds__(256) void gemm_ep64(const bf16* __restrict__ A,
                                                 const bf16* __restrict__ BT,
                                                 const float* __restrict__ bias,
                                                 const float* __restrict__ res,
                                                 void* __restrict__ outp,
                                                 int N, int K) {
    __shared__ bf16 As[2 * 64 * 32];
    __shared__ bf16 Bs[2 * 128 * 32];
    int bm = blockIdx.y * 64, bn = blockIdx.x * 128;
    int tid = threadIdx.x, wid = tid >> 6, lane = tid & 63, quad = lane >> 4, lid = lane & 15;
    int wm = (wid >> 1) * 32, wn = (wid & 1) * 64;
    f32x4 acc[2][4] = {};
    int ra = tid >> 2, ca = (tid & 3) ^ ((ra >> 1) & 3);
    int s0 = tid, s1 = tid + 256;
    int rb0 = s0 >> 2, cb0 = (s0 & 3) ^ ((rb0 >> 1) & 3);
    int rb1 = s1 >> 2, cb1 = (s1 & 3) ^ ((rb1 >> 1) & 3);
    const bf16* Ap = A + (size_t)(bm + ra) * K + ca * 8;
    const bf16* B0 = BT + (size_t)(bn + rb0) * K + cb0 * 8;
    const bf16* B1 = BT + (size_t)(bn + rb1) * K + cb1 * 8;
    int rdc = quad ^ ((lid >> 1) & 3);
    g2l16(Ap, As + tid * 8);
    g2l16(B0, Bs + s0 * 8);
    g2l16(B1, Bs + s1 * 8);
    for (int k0 = 0; k0 < K; k0 += 32) {
        __syncthreads();
        int cur = (k0 >> 5) & 1;
        if (k0 + 32 < K) {
            g2l16(Ap + k0 + 32, As + (cur ^ 1) * 2048 + tid * 8);
            g2l16(B0 + k0 + 32, Bs + (cur ^ 1) * 4096 + s0 * 8);
            g2l16(B1 + k0 + 32, Bs + (cur ^ 1) * 4096 + s1 * 8);
        }
        const bf16* Ac = As + cur * 2048;
        const bf16* Bc = Bs + cur * 4096;
        bf16x8 af[2], bfr[4];
#pragma unroll
        for (int i = 0; i < 2; ++i) af[i]  = *(const bf16x8*)&Ac[(wm + i * 16 + lid) * 32 + rdc * 8];
#pragma unroll
        for (int j = 0; j < 4; ++j) bfr[j] = *(const bf16x8*)&Bc[(wn + j * 16 + lid) * 32 + rdc * 8];
#pragma unroll
        for (int i = 0; i < 2; ++i)
#pragma unroll
            for (int j = 0; j < 4; ++j)
                acc[i][j] = MFMA16(af[i], bfr[j], acc[i][j]);
    }
#pragma unroll
    for (int j = 0; j < 4; ++j) {
        int col = bn + wn + j * 16 + lid;
        float bb = bias[col];
#pragma unroll
        for (int i = 0; i < 2; ++i) {
#pragma unroll
            for (int r = 0; r < 4; ++r) {
                int row = bm + wm + i * 16 + quad * 4 + r;
                float v = acc[i][j][r] + bb;
                if (EPI == 2) {
                    ((float*)outp)[(size_t)row * N + col] = res[(size_t)row * N + col] + v;
                } else {
                    ((bf16*)outp)[(size_t)row * N + col] = f2b(fmaxf(v, 0.f));
                }
            }
        }
    }
}

// ---------------- flash attention, k-chunk partials (KCH=2) -----------------
// grid (SS/64, B*NH, KCH) = 1536 blocks = exactly 6 resident/CU (LDS 25.6KB).
// part layout TRANSPOSED: [kc][bh][DK][SS] so the C-layout epilogue (4
// consecutive q per lane at fixed d) packs into 4 ushort4 stores.
__global__ __launch_bounds__(256) void attn_part(const bf16* __restrict__ qb,
                                                 const bf16* __restrict__ kb,
                                                 const bf16* __restrict__ vtb,
                                                 const int* __restrict__ mask,
                                                 bf16* __restrict__ part,
                                                 float* __restrict__ lws) {
    __shared__ bf16 Ks[64 * 64];
    __shared__ bf16 VTs[64 * 64];
    __shared__ bf16 Ps[64 * 72];   // [q][k], stride 72 -> b128 reads benign
    int bh = blockIdx.y;
    int b = bh / NH;
    int q0 = blockIdx.x * 64;
    int kc = blockIdx.z;
    const bf16* Kp = kb  + (size_t)bh * SS * DK;
    const bf16* VT = vtb + (size_t)bh * DK * SS;
    int tid = threadIdx.x, wid = tid >> 6, lane = tid & 63, quad = lane >> 4, lid = lane & 15;

    int s0 = tid, s1 = tid + 256;
    int r0 = s0 >> 3, c0 = (s0 & 7) ^ (r0 & 7);
    int r1 = s1 >> 3, c1 = (s1 & 7) ^ (r1 & 7);

    // Q fragment to registers; same lane mapping serves as B-operand for S^T
    const bf16* Qrow = qb + ((size_t)bh * SS + q0 + wid * 16 + lid) * DK;
    bf16x8 qf0 = *(const bf16x8*)&Qrow[quad * 8];
    bf16x8 qf1 = *(const bf16x8*)&Qrow[32 + quad * 8];

    bf16x8 ones;
#pragma unroll
    for (int i = 0; i < 8; ++i) ones[i] = (short)0x3F80;   // bf16 1.0

    int rdc  = quad ^ (lid & 7);
    int rdc2 = rdc ^ 4;
    const int* mrow = mask + b * SS;

    f32x4 accv[4] = {};
    f32x4 accl = {};

    for (int t = kc * (SS / 64 / KCH); t < (kc + 1) * (SS / 64 / KCH); ++t) {
        int k0 = t * 64;
        __syncthreads();
        g2l16(Kp + (size_t)(k0 + r0) * DK + c0 * 8, Ks + s0 * 8);
        g2l16(Kp + (size_t)(k0 + r1) * DK + c1 * 8, Ks + s1 * 8);
        g2l16(VT + (size_t)r0 * SS + k0 + c0 * 8, VTs + s0 * 8);
        g2l16(VT + (size_t)r1 * SS + k0 + c1 * 8, VTs + s1 * 8);
        __syncthreads();

        // S^T: lane holds k = ns*16 + quad*4 + r, q = wid*16 + lid
#pragma unroll
        for (int ns = 0; ns < 4; ++ns) {
            bf16x8 kf0 = *(const bf16x8*)&Ks[(ns * 16 + lid) * 64 + rdc * 8];
            bf16x8 kf1 = *(const bf16x8*)&Ks[(ns * 16 + lid) * 64 + rdc2 * 8];
            f32x4 st = {};
            st = MFMA16(kf0, qf0, st);
            st = MFMA16(kf1, qf1, st);
            int4 mk = *(const int4*)&mrow[k0 + ns * 16 + quad * 4];
            float p0 = mk.x ? EXP2F(st[0]) : 0.f;
            float p1 = mk.y ? EXP2F(st[1]) : 0.f;
            float p2 = mk.z ? EXP2F(st[2]) : 0.f;
            float p3 = mk.w ? EXP2F(st[3]) : 0.f;
            __hip_bfloat162 h01 = __float22bfloat162_rn(make_float2(p0, p1));
            __hip_bfloat162 h23 = __float22bfloat162_rn(make_float2(p2, p3));
            uint2 pw;
            pw.x = *(unsigned int*)&h01;
            pw.y = *(unsigned int*)&h23;
            *(uint2*)&Ps[(wid * 16 + lid) * 72 + ns * 16 + quad * 4] = pw;
        }

        // P A-frags (same-wave round trip, no barrier)
        bf16x8 pa0 = *(const bf16x8*)&Ps[(wid * 16 + lid) * 72 + quad * 8];
        bf16x8 pa1 = *(const bf16x8*)&Ps[(wid * 16 + lid) * 72 + 32 + quad * 8];

        // denominator via ones-MFMA: accl[r] = sum_k P[q=wid*16+quad*4+r][k]
        accl = MFMA16(pa0, ones, accl);
        accl = MFMA16(pa1, ones, accl);

#pragma unroll
        for (int ds = 0; ds < 4; ++ds) {
            bf16x8 vf0 = *(const bf16x8*)&VTs[(ds * 16 + lid) * 64 + rdc * 8];
            bf16x8 vf1 = *(const bf16x8*)&VTs[(ds * 16 + lid) * 64 + rdc2 * 8];
            accv[ds] = MFMA16(pa0, vf0, accv[ds]);
            accv[ds] = MFMA16(pa1, vf1, accv[ds]);
        }
    }

    if (lid == 0) {
#pragma unroll
        for (int r = 0; r < 4; ++r)
            lws[((size_t)kc * (2 * NH) + bh) * SS + q0 + wid * 16 + quad * 4 + r] = accl[r];
    }

    // raw partial context, transposed layout [kc][bh][d][s]: packed ushort4
    bf16* pb = part + ((size_t)kc * (2 * NH) + bh) * DK * SS;
    int qbase = q0 + wid * 16 + quad * 4;
#pragma unroll
    for (int ds = 0; ds < 4; ++ds) {
        int d = ds * 16 + lid;
        ushort4 pk;
        pk.x = f2b_bits(accv[ds][0]);
        pk.y = f2b_bits(accv[ds][1]);
        pk.z = f2b_bits(accv[ds][2]);
        pk.w = f2b_bits(accv[ds][3]);
        *(ushort4*)&pb[(size_t)d * SS + qbase] = pk;
    }
}

// combine with LDS transpose: block per (64-q tile, bh).
// reads part[kc][bh][d][q] coalesced along q, writes ctx rows coalesced.
__global__ __launch_bounds__(256) void attn_combine(const bf16* __restrict__ part,
                                                    const float* __restrict__ lws,
                                                    bf16* __restrict__ ctx) {
    __shared__ float tile[64][66];
    __shared__ float linv[64];
    int bh = blockIdx.y;
    int b = bh / NH, h = bh % NH;
    int q0 = blockIdx.x * 64;
    int tid = threadIdx.x;

    if (tid < 64) {
        float l = 0.f;
#pragma unroll
        for (int kc = 0; kc < KCH; ++kc)
            l += lws[((size_t)kc * (2 * NH) + bh) * SS + q0 + tid];
        linv[tid] = 1.f / l;
    }

    // read phase: thread -> d = tid>>2, 16 q starting at (tid&3)*16
    int d = tid >> 2, qs = (tid & 3) * 16;
    const bf16* p0 = part + (((size_t)0 * (2 * NH) + bh) * DK + d) * SS + q0 + qs;
    const bf16* p1 = part + (((size_t)1 * (2 * NH) + bh) * DK + d) * SS + q0 + qs;
    bf16x8 a0 = *(const bf16x8*)p0;
    bf16x8 a1 = *(const bf16x8*)(p0 + 8);
    bf16x8 b0 = *(const bf16x8*)p1;
    bf16x8 b1 = *(const bf16x8*)(p1 + 8);
#pragma unroll
    for (int i = 0; i < 8; ++i) {
        tile[d][qs + i]     = b2f(((const bf16*)&a0)[i]) + b2f(((const bf16*)&b0)[i]);
        tile[d][qs + 8 + i] = b2f(((const bf16*)&a1)[i]) + b2f(((const bf16*)&b1)[i]);
    }
    __syncthreads();

    // write phase: thread -> q = tid>>2, 16 d starting at (tid&3)*16
    int q = tid >> 2, ds2 = (tid & 3) * 16;
    float rl = linv[q];
    unsigned int wv[8];
#pragma unroll
    for (int i = 0; i < 8; ++i) {
        __hip_bfloat162 hh = __float22bfloat162_rn(
            make_float2(tile[ds2 + 2 * i][q] * rl, tile[ds2 + 2 * i + 1][q] * rl));
        wv[i] = *(unsigned int*)&hh;
    }
    bf16* crow = ctx + (size_t)(b * SS + q0 + q) * DM + h * DK + ds2;
    uint4 u0 = {wv[0], wv[1], wv[2], wv[3]};
    uint4 u1 = {wv[4], wv[5], wv[6], wv[7]};
    *(uint4*)&crow[0] = u0;
    *(uint4*)&crow[8] = u1;
}

// ---------------- host launch ----------------------------------------------
extern "C" void kernel_launch(void* const* d_in, const int* in_sizes, int n_in,
                              void* d_out, int out_size, void* d_ws, size_t ws_size,
                              hipStream_t stream) {
    const float* x    = (const float*)d_in[0];
    const int*   mask = (const int*)d_in[1];
    const float* Wq   = (const float*)d_in[2];
    const float* bq   = (const float*)d_in[3];
    const float* Wk   = (const float*)d_in[4];
    const float* bk   = (const float*)d_in[5];
    const float* Wv   = (const float*)d_in[6];
    const float* bv   = (const float*)d_in[7];
    const float* Wo   = (const float*)d_in[8];
    const float* bo   = (const float*)d_in[9];
    const float* ln1a = (const float*)d_in[10];
    const float* ln1b = (const float*)d_in[11];
    const float* W1   = (const float*)d_in[12];
    const float* b1   = (const float*)d_in[13];
    const float* W2   = (const float*)d_in[14];
    const float* b2   = (const float*)d_in[15];
    const float* ln2a = (const float*)d_in[16];
    const float* ln2b = (const float*)d_in[17];
    float* out = (float*)d_out;

    char* w = (char*)d_ws;
    bf16* h   = (bf16*)w; w += (size_t)NTOK * DM * 2;
    bf16* qb  = (bf16*)w; w += (size_t)NTOK * DM * 2;
    bf16* kb  = (bf16*)w; w += (size_t)NTOK * DM * 2;
    bf16* vtb = (bf16*)w; w += (size_t)NTOK * DM * 2;
    bf16* ctx = (bf16*)w; w += (size_t)NTOK * DM * 2;
    bf16* h2  = (bf16*)w; w += (size_t)NTOK * DM * 2;
    bf16* ffa = (bf16*)w; w += (size_t)NTOK * DFF * 2;   // also attn partials (temporally disjoint)
    float* x1 = (float*)w; w += (size_t)NTOK * DM * 4;   // also attn l-partials (temporally disjoint)
    bf16* WqT = (bf16*)w; w += (size_t)DM * DM * 2;
    bf16* WkT = (bf16*)w; w += (size_t)DM * DM * 2;
    bf16* WvT = (bf16*)w; w += (size_t)DM * DM * 2;
    bf16* WoT = (bf16*)w; w += (size_t)DM * DM * 2;
    bf16* W1T = (bf16*)w; w += (size_t)DM * DFF * 2;
    bf16* W2T = (bf16*)w; w += (size_t)DM * DFF * 2;

    bf16*  part = ffa;          // KCH*2*NH*DK*SS*2 = 12.6 MB <= NTOK*DFF*2 (24 MB)
    float* lws  = x1;           // KCH*24*SS*4 = 384 KB < NTOK*DM*4

    transpose_all<<<6912, 256, 0, stream>>>(Wq, Wk, Wv, Wo, W1, W2,
                                            WqT, WkT, WvT, WoT, W1T, W2T);

    ln_fwd<<<NTOK / 4, 256, 0, stream>>>(x, ln1a, ln1b, h);
    gemm_qkv<<<dim3(18, 32), 256, 0, stream>>>(h, WqT, WkT, WvT, bq, bk, bv, qb, kb, vtb);
    attn_part<<<dim3(SS / 64, 2 * NH, KCH), 256, 0, stream>>>(qb, kb, vtb, mask, part, lws);
    attn_combine<<<dim3(SS / 64, 2 * NH), 256, 0, stream>>>(part, lws, ctx);
    gemm_ep64<2><<<dim3(6, 64), 256, 0, stream>>>(ctx, WoT, bo, x, (void*)x1, DM, DM);
    ln_fwd<<<NTOK / 4, 256, 0, stream>>>(x1, ln2a, ln2b, h2);
    gemm_ep<3><<<dim3(24, 32), 256, 0, stream>>>(h2, W1T, b1, nullptr, (void*)ffa, DFF, DM);
    gemm_ep64<2><<<dim3(6, 64), 256, 0, stream>>>(ffa, W2T, b2, x1, (void*)out, DM, DFF);
}